// Round 1
// baseline (340.770 us; speedup 1.0000x reference)
//
#include <hip/hip_runtime.h>
#include <stdint.h>

#define NEXP 8
#define DD   512
#define BM   128
#define BN   128
#define BK   32

typedef short s16x8 __attribute__((ext_vector_type(8)));
typedef float f32x4 __attribute__((ext_vector_type(4)));

static __device__ __forceinline__ unsigned short f2bf(float f) {
    union { float f; unsigned u; } v; v.f = f;
    unsigned r = v.u + 0x7FFFu + ((v.u >> 16) & 1u);   // round-to-nearest-even
    return (unsigned short)(r >> 16);
}

// ---------------- bucketing kernels ----------------

__global__ void hist_kernel(const int* __restrict__ z, int* __restrict__ counts, int T) {
    __shared__ int lc[NEXP];
    int tid = threadIdx.x;
    if (tid < NEXP) lc[tid] = 0;
    __syncthreads();
    int t = blockIdx.x * blockDim.x + tid;
    if (t < T) atomicAdd(&lc[z[t]], 1);
    __syncthreads();
    if (tid < NEXP) atomicAdd(&counts[tid], lc[tid]);
}

__global__ void scan_kernel(const int* __restrict__ counts, int* __restrict__ cursors,
                            int4* __restrict__ table, int max_tiles) {
    if (blockIdx.x == 0 && threadIdx.x == 0) {
        int off = 0, tidx = 0;
        for (int e = 0; e < NEXP; e++) {
            cursors[e] = off;
            int c = counts[e];
            for (int r = 0; r < c; r += BM) {
                int4 ent; ent.x = e; ent.y = off + r; ent.z = c - r; ent.w = 0;
                table[tidx++] = ent;
            }
            off += c;
        }
        for (int i = tidx; i < max_tiles; i++) {
            int4 ent; ent.x = -1; ent.y = 0; ent.z = 0; ent.w = 0;
            table[i] = ent;
        }
    }
}

__global__ void scatter_kernel(const int* __restrict__ z, int* __restrict__ cursors,
                               int* __restrict__ token_index, float* __restrict__ zout, int T) {
    __shared__ int lc[NEXP];
    __shared__ int lbase[NEXP];
    int tid = threadIdx.x;
    if (tid < NEXP) lc[tid] = 0;
    __syncthreads();
    int t = blockIdx.x * blockDim.x + tid;
    int e = 0, rank = 0;
    if (t < T) {
        e = z[t];
        rank = atomicAdd(&lc[e], 1);
        zout[t] = (float)e;            // output 0: z as float
    }
    __syncthreads();
    if (tid < NEXP) lbase[tid] = atomicAdd(&cursors[tid], lc[tid]);
    __syncthreads();
    if (t < T) token_index[lbase[e] + rank] = t;
}

// W [8][k=512][n=512] f32  ->  Wt [8][n=512][k=512] bf16 (transposed, contiguous-k rows)
__global__ void convw_kernel(const float* __restrict__ W, unsigned short* __restrict__ Wt) {
    __shared__ float tile[32][33];
    int e = blockIdx.z, k0 = blockIdx.x * 32, n0 = blockIdx.y * 32;
    int tid = threadIdx.x;
    const float* We = W + (size_t)e * DD * DD;
    unsigned short* WtE = Wt + (size_t)e * DD * DD;
    int c = tid & 31, r0 = tid >> 5;
#pragma unroll
    for (int i = 0; i < 4; i++) {
        int kr = r0 + 8 * i;
        tile[kr][c] = We[(size_t)(k0 + kr) * DD + n0 + c];
    }
    __syncthreads();
#pragma unroll
    for (int i = 0; i < 4; i++) {
        int nr = r0 + 8 * i;
        WtE[(size_t)(n0 + nr) * DD + k0 + c] = f2bf(tile[c][nr]);
    }
}

// ---------------- grouped GEMM ----------------
// Per block: 128 tokens (one expert segment tile) x 128 output cols.
// LDS row stride = 40 bf16 = 80B (multiple of 16B -> aligned b128, conflict-free pattern).

__global__ __launch_bounds__(256) void gemm_kernel(
    const float* __restrict__ x,                // [T][512] f32
    const unsigned short* __restrict__ Wt,      // [8][n][k] bf16
    const float* __restrict__ bias,             // [8][512] f32
    const int* __restrict__ token_index,
    const int4* __restrict__ table,
    float* __restrict__ y)                      // [T][512] f32
{
    int4 te = table[blockIdx.x];
    int e = te.x;
    if (e < 0) return;
    int base = te.y;
    int rows_valid = te.z < BM ? te.z : BM;
    int n0 = blockIdx.y * BN;

    __shared__ unsigned short Als[BM * 40];
    __shared__ unsigned short Bls[BN * 40];

    const int tid  = threadIdx.x;
    const int lane = tid & 63;
    const int wave = tid >> 6;
    const int wm = (wave & 1) * 64;
    const int wn = (wave >> 1) * 64;

    // A staging: thread covers k-quad a_q of rows a_r0 + 32*i
    const int a_q  = tid & 7;
    const int a_r0 = tid >> 3;
    int tok[4];
#pragma unroll
    for (int i = 0; i < 4; i++) {
        int r = a_r0 + 32 * i;
        int rr = (r < rows_valid) ? r : 0;
        tok[i] = token_index[base + rr];
    }
    // B staging: thread covers 16B chunk b_c of rows b_n0 + 64*i
    const int b_c  = tid & 3;
    const int b_n0 = tid >> 2;
    const unsigned short* WtE = Wt + (size_t)e * DD * DD;

    f32x4 acc[4][4];
#pragma unroll
    for (int i = 0; i < 4; i++)
#pragma unroll
        for (int j = 0; j < 4; j++) acc[i][j] = (f32x4){0.f, 0.f, 0.f, 0.f};

    const int quad = lane >> 4;
    const int lrow = lane & 15;

    for (int k0 = 0; k0 < DD; k0 += BK) {
        __syncthreads();
        // stage A (gather + f32->bf16)
#pragma unroll
        for (int i = 0; i < 4; i++) {
            int r = a_r0 + 32 * i;
            const float4 v = *(const float4*)(x + (size_t)tok[i] * DD + k0 + a_q * 4);
            unsigned u0 = (unsigned)f2bf(v.x) | ((unsigned)f2bf(v.y) << 16);
            unsigned u1 = (unsigned)f2bf(v.z) | ((unsigned)f2bf(v.w) << 16);
            uint2 p; p.x = u0; p.y = u1;
            *(uint2*)(&Als[r * 40 + a_q * 4]) = p;
        }
        // stage B (already bf16, contiguous)
#pragma unroll
        for (int i = 0; i < 2; i++) {
            int n = b_n0 + 64 * i;
            uint4 v = *(const uint4*)(WtE + (size_t)(n0 + n) * DD + k0 + b_c * 8);
            *(uint4*)(&Bls[n * 40 + b_c * 8]) = v;
        }
        __syncthreads();

        s16x8 af[4], bq[4];
#pragma unroll
        for (int i = 0; i < 4; i++)
            af[i] = *(const s16x8*)(&Als[(wm + i * 16 + lrow) * 40 + quad * 8]);
#pragma unroll
        for (int j = 0; j < 4; j++)
            bq[j] = *(const s16x8*)(&Bls[(wn + j * 16 + lrow) * 40 + quad * 8]);
#pragma unroll
        for (int i = 0; i < 4; i++)
#pragma unroll
            for (int j = 0; j < 4; j++)
                acc[i][j] = __builtin_amdgcn_mfma_f32_16x16x32_bf16(af[i], bq[j], acc[i][j], 0, 0, 0);
    }

    // epilogue: C/D layout col=lane&15, row=quad*4+reg
    const int lcol = lane & 15;
    float bv[4];
#pragma unroll
    for (int j = 0; j < 4; j++) bv[j] = bias[e * DD + n0 + wn + j * 16 + lcol];
#pragma unroll
    for (int i = 0; i < 4; i++) {
#pragma unroll
        for (int reg = 0; reg < 4; reg++) {
            int r = wm + i * 16 + quad * 4 + reg;
            if (r < rows_valid) {
                int t = token_index[base + r];
                float* yr = y + (size_t)t * DD + n0 + wn + lcol;
#pragma unroll
                for (int j = 0; j < 4; j++)
                    yr[j * 16] = acc[i][j][reg] + bv[j];
            }
        }
    }
}

// ---------------- host ----------------

extern "C" void kernel_launch(void* const* d_in, const int* in_sizes, int n_in,
                              void* d_out, int out_size, void* d_ws, size_t ws_size,
                              hipStream_t stream) {
    const int*   z = (const int*)d_in[0];
    const float* x = (const float*)d_in[1];
    const float* W = (const float*)d_in[2];
    const float* b = (const float*)d_in[3];
    const int T = in_sizes[0];                 // 65536

    float* zout = (float*)d_out;               // [T] float(z)
    float* y    = (float*)d_out + T;           // [T][512]

    char* ws = (char*)d_ws;
    int*  counts      = (int*)ws;              // 8 ints
    int*  cursors     = (int*)(ws + 32);       // 8 ints
    int4* table       = (int4*)(ws + 256);     // up to 1024 entries
    int*  token_index = (int*)(ws + 16640);    // T ints
    unsigned short* Wt = (unsigned short*)(ws + 294912); // 8*512*512 bf16 = 4MB

    const int max_tiles = T / BM + NEXP;       // 520

    hipMemsetAsync(ws, 0, 64, stream);
    hist_kernel<<<(T + 255) / 256, 256, 0, stream>>>(z, counts, T);
    convw_kernel<<<dim3(DD / 32, DD / 32, NEXP), 256, 0, stream>>>(W, Wt);
    scan_kernel<<<1, 1, 0, stream>>>(counts, cursors, table, max_tiles);
    scatter_kernel<<<(T + 255) / 256, 256, 0, stream>>>(z, cursors, token_index, zout, T);
    gemm_kernel<<<dim3(max_tiles, DD / BN), 256, 0, stream>>>(x, Wt, b, token_index, table, y);
}

// Round 2
// 333.730 us; speedup vs baseline: 1.0211x; 1.0211x over previous
//
#include <hip/hip_runtime.h>
#include <stdint.h>

#define NEXP 8
#define DD   512
#define BM   128
#define BN   128

typedef short s16x8 __attribute__((ext_vector_type(8)));
typedef float f32x4 __attribute__((ext_vector_type(4)));

static __device__ __forceinline__ unsigned short f2bf(float f) {
    union { float f; unsigned u; } v; v.f = f;
    unsigned r = v.u + 0x7FFFu + ((v.u >> 16) & 1u);   // round-to-nearest-even
    return (unsigned short)(r >> 16);
}

// ---------------- bucketing kernels ----------------

__global__ void hist_kernel(const int* __restrict__ z, int* __restrict__ counts, int T) {
    __shared__ int lc[NEXP];
    int tid = threadIdx.x;
    if (tid < NEXP) lc[tid] = 0;
    __syncthreads();
    int t = blockIdx.x * blockDim.x + tid;
    if (t < T) atomicAdd(&lc[z[t]], 1);
    __syncthreads();
    if (tid < NEXP) atomicAdd(&counts[tid], lc[tid]);
}

// parallel: 1 block, 256 threads (R1 version was 1 serial thread)
__global__ void scan_kernel(const int* __restrict__ counts, int* __restrict__ cursors,
                            int4* __restrict__ table, int max_tiles) {
    __shared__ int off[NEXP + 1];
    __shared__ int tb[NEXP + 1];
    int tid = threadIdx.x;
    if (tid == 0) {
        int o = 0, tbs = 0;
        for (int e = 0; e < NEXP; e++) {
            off[e] = o; tb[e] = tbs;
            cursors[e] = o;
            int c = counts[e];
            o += c;
            tbs += (c + BM - 1) / BM;
        }
        off[NEXP] = o; tb[NEXP] = tbs;
    }
    __syncthreads();
    for (int idx = tid; idx < max_tiles; idx += blockDim.x) {
        int4 ent; ent.x = -1; ent.y = 0; ent.z = 0; ent.w = 0;
#pragma unroll
        for (int e = 0; e < NEXP; e++) {
            if (idx >= tb[e] && idx < tb[e + 1]) {
                int r = (idx - tb[e]) * BM;
                ent.x = e; ent.y = off[e] + r; ent.z = (off[e + 1] - off[e]) - r;
            }
        }
        table[idx] = ent;
    }
}

__global__ void scatter_kernel(const int* __restrict__ z, int* __restrict__ cursors,
                               int* __restrict__ token_index, float* __restrict__ zout, int T) {
    __shared__ int lc[NEXP];
    __shared__ int lbase[NEXP];
    int tid = threadIdx.x;
    if (tid < NEXP) lc[tid] = 0;
    __syncthreads();
    int t = blockIdx.x * blockDim.x + tid;
    int e = 0, rank = 0;
    if (t < T) {
        e = z[t];
        rank = atomicAdd(&lc[e], 1);
        zout[t] = (float)e;            // output 0: z as float
    }
    __syncthreads();
    if (tid < NEXP) lbase[tid] = atomicAdd(&cursors[tid], lc[tid]);
    __syncthreads();
    if (t < T) token_index[lbase[e] + rank] = t;
}

// xg[i][k] = bf16(x[token_index[i]][k])  — one wave per row, fully coalesced writes
__global__ __launch_bounds__(256) void gather_kernel(const float* __restrict__ x,
                                                     const int* __restrict__ token_index,
                                                     unsigned short* __restrict__ xg, int T) {
    int i = blockIdx.x * 4 + (threadIdx.x >> 6);
    if (i >= T) return;
    int lane = threadIdx.x & 63;
    int t = token_index[i];
    const float4* src = (const float4*)(x + (size_t)t * DD) + lane * 2;
    float4 v0 = src[0], v1 = src[1];
    uint4 p;
    p.x = (unsigned)f2bf(v0.x) | ((unsigned)f2bf(v0.y) << 16);
    p.y = (unsigned)f2bf(v0.z) | ((unsigned)f2bf(v0.w) << 16);
    p.z = (unsigned)f2bf(v1.x) | ((unsigned)f2bf(v1.y) << 16);
    p.w = (unsigned)f2bf(v1.z) | ((unsigned)f2bf(v1.w) << 16);
    *(uint4*)(xg + (size_t)i * DD + lane * 8) = p;
}

// W [8][k=512][n=512] f32  ->  Wt [8][n=512][k=512] bf16 (transposed, contiguous-k rows)
__global__ void convw_kernel(const float* __restrict__ W, unsigned short* __restrict__ Wt) {
    __shared__ float tile[32][33];
    int e = blockIdx.z, k0 = blockIdx.x * 32, n0 = blockIdx.y * 32;
    int tid = threadIdx.x;
    const float* We = W + (size_t)e * DD * DD;
    unsigned short* WtE = Wt + (size_t)e * DD * DD;
    int c = tid & 31, r0 = tid >> 5;
#pragma unroll
    for (int i = 0; i < 4; i++) {
        int kr = r0 + 8 * i;
        tile[kr][c] = We[(size_t)(k0 + kr) * DD + n0 + c];
    }
    __syncthreads();
#pragma unroll
    for (int i = 0; i < 4; i++) {
        int nr = r0 + 8 * i;
        WtE[(size_t)(n0 + nr) * DD + k0 + c] = f2bf(tile[c][nr]);
    }
}

// ---------------- grouped GEMM, m97-style ----------------
// BK=64, LDS stride 64 bf16 (128B, no pad — required by global_load_lds).
// Chunk-XOR swizzle (chunk ^ (row&7)) applied via the per-lane GLOBAL address,
// so ds_read_b128 fragment reads are 2-way (free) instead of 16-way conflicted.

__global__ __launch_bounds__(256) void gemm2_kernel(
    const unsigned short* __restrict__ xg,      // [T][512] bf16, grouped by expert
    const unsigned short* __restrict__ Wt,      // [8][n][k] bf16
    const float* __restrict__ bias,             // [8][512] f32
    const int* __restrict__ token_index,
    const int4* __restrict__ table,
    float* __restrict__ y)                      // [T][512] f32
{
    int4 te = table[blockIdx.x];
    int e = te.x;
    if (e < 0) return;
    const int base = te.y;
    const int rows_valid = te.z < BM ? te.z : BM;
    const int n0 = blockIdx.y * BN;

    __shared__ unsigned short Als[BM * 64];     // 16 KB
    __shared__ unsigned short Bls[BN * 64];     // 16 KB

    const int tid  = threadIdx.x;
    const int lane = tid & 63;
    const int wave = tid >> 6;
    const int wm = (wave & 1) * 64;
    const int wn = (wave >> 1) * 64;

    // staging slots: slot s = wave*256 + q*64 + lane; row = s>>3, chunk-slot = s&7;
    // global chunk = cs ^ (row&7)  (the swizzle)
    int srow[4], schunk[4];
#pragma unroll
    for (int q = 0; q < 4; q++) {
        int s = wave * 256 + q * 64 + lane;
        srow[q]   = s >> 3;
        schunk[q] = (s & 7) ^ ((s >> 3) & 7);
    }

    const unsigned short* WtE = Wt + (size_t)e * DD * DD;

    f32x4 acc[4][4];
#pragma unroll
    for (int i = 0; i < 4; i++)
#pragma unroll
        for (int j = 0; j < 4; j++) acc[i][j] = (f32x4){0.f, 0.f, 0.f, 0.f};

    const int quad = lane >> 4;
    const int lrow = lane & 15;

    for (int k0 = 0; k0 < DD; k0 += 64) {
        __syncthreads();
#pragma unroll
        for (int q = 0; q < 4; q++) {
            const int r = srow[q], c = schunk[q];
            const unsigned short* ga = xg + (size_t)(base + r) * DD + k0 + c * 8;
            const unsigned short* gb = WtE + (size_t)(n0 + r) * DD + k0 + c * 8;
            unsigned short* la = &Als[(size_t)(wave * 256 + q * 64) * 8];
            unsigned short* lb = &Bls[(size_t)(wave * 256 + q * 64) * 8];
            __builtin_amdgcn_global_load_lds((const __attribute__((address_space(1))) void*)ga,
                                             (__attribute__((address_space(3))) void*)la, 16, 0, 0);
            __builtin_amdgcn_global_load_lds((const __attribute__((address_space(1))) void*)gb,
                                             (__attribute__((address_space(3))) void*)lb, 16, 0, 0);
        }
        __syncthreads();

#pragma unroll
        for (int ks = 0; ks < 2; ks++) {
            s16x8 af[4], bq[4];
#pragma unroll
            for (int i = 0; i < 4; i++) {
                int r = wm + i * 16 + lrow;
                af[i] = *(const s16x8*)(&Als[r * 64 + (((quad + 4 * ks) ^ (r & 7)) * 8)]);
            }
#pragma unroll
            for (int j = 0; j < 4; j++) {
                int r = wn + j * 16 + lrow;
                bq[j] = *(const s16x8*)(&Bls[r * 64 + (((quad + 4 * ks) ^ (r & 7)) * 8)]);
            }
#pragma unroll
            for (int i = 0; i < 4; i++)
#pragma unroll
                for (int j = 0; j < 4; j++)
                    acc[i][j] = __builtin_amdgcn_mfma_f32_16x16x32_bf16(af[i], bq[j], acc[i][j], 0, 0, 0);
        }
    }

    // epilogue: C/D layout col=lane&15, row=quad*4+reg
    const int lcol = lane & 15;
    float bv[4];
#pragma unroll
    for (int j = 0; j < 4; j++) bv[j] = bias[e * DD + n0 + wn + j * 16 + lcol];
#pragma unroll
    for (int i = 0; i < 4; i++) {
#pragma unroll
        for (int reg = 0; reg < 4; reg++) {
            int r = wm + i * 16 + quad * 4 + reg;
            if (r < rows_valid) {
                int t = token_index[base + r];
                float* yr = y + (size_t)t * DD + n0 + wn + lcol;
#pragma unroll
                for (int j = 0; j < 4; j++)
                    yr[j * 16] = acc[i][j][reg] + bv[j];
            }
        }
    }
}

// ---------------- fallback GEMM (R1, passes with small ws) ----------------

__global__ __launch_bounds__(256) void gemm_kernel(
    const float* __restrict__ x, const unsigned short* __restrict__ Wt,
    const float* __restrict__ bias, const int* __restrict__ token_index,
    const int4* __restrict__ table, float* __restrict__ y)
{
    int4 te = table[blockIdx.x];
    int e = te.x;
    if (e < 0) return;
    int base = te.y;
    int rows_valid = te.z < BM ? te.z : BM;
    int n0 = blockIdx.y * BN;

    __shared__ unsigned short Als[BM * 40];
    __shared__ unsigned short Bls[BN * 40];

    const int tid  = threadIdx.x;
    const int lane = tid & 63;
    const int wave = tid >> 6;
    const int wm = (wave & 1) * 64;
    const int wn = (wave >> 1) * 64;

    const int a_q  = tid & 7;
    const int a_r0 = tid >> 3;
    int tok[4];
#pragma unroll
    for (int i = 0; i < 4; i++) {
        int r = a_r0 + 32 * i;
        int rr = (r < rows_valid) ? r : 0;
        tok[i] = token_index[base + rr];
    }
    const int b_c  = tid & 3;
    const int b_n0 = tid >> 2;
    const unsigned short* WtE = Wt + (size_t)e * DD * DD;

    f32x4 acc[4][4];
#pragma unroll
    for (int i = 0; i < 4; i++)
#pragma unroll
        for (int j = 0; j < 4; j++) acc[i][j] = (f32x4){0.f, 0.f, 0.f, 0.f};

    const int quad = lane >> 4;
    const int lrow = lane & 15;

    for (int k0 = 0; k0 < DD; k0 += 32) {
        __syncthreads();
#pragma unroll
        for (int i = 0; i < 4; i++) {
            int r = a_r0 + 32 * i;
            const float4 v = *(const float4*)(x + (size_t)tok[i] * DD + k0 + a_q * 4);
            unsigned u0 = (unsigned)f2bf(v.x) | ((unsigned)f2bf(v.y) << 16);
            unsigned u1 = (unsigned)f2bf(v.z) | ((unsigned)f2bf(v.w) << 16);
            uint2 p; p.x = u0; p.y = u1;
            *(uint2*)(&Als[r * 40 + a_q * 4]) = p;
        }
#pragma unroll
        for (int i = 0; i < 2; i++) {
            int n = b_n0 + 64 * i;
            uint4 v = *(const uint4*)(WtE + (size_t)(n0 + n) * DD + k0 + b_c * 8);
            *(uint4*)(&Bls[n * 40 + b_c * 8]) = v;
        }
        __syncthreads();

        s16x8 af[4], bq[4];
#pragma unroll
        for (int i = 0; i < 4; i++)
            af[i] = *(const s16x8*)(&Als[(wm + i * 16 + lrow) * 40 + quad * 8]);
#pragma unroll
        for (int j = 0; j < 4; j++)
            bq[j] = *(const s16x8*)(&Bls[(wn + j * 16 + lrow) * 40 + quad * 8]);
#pragma unroll
        for (int i = 0; i < 4; i++)
#pragma unroll
            for (int j = 0; j < 4; j++)
                acc[i][j] = __builtin_amdgcn_mfma_f32_16x16x32_bf16(af[i], bq[j], acc[i][j], 0, 0, 0);
    }

    const int lcol = lane & 15;
    float bv[4];
#pragma unroll
    for (int j = 0; j < 4; j++) bv[j] = bias[e * DD + n0 + wn + j * 16 + lcol];
#pragma unroll
    for (int i = 0; i < 4; i++) {
#pragma unroll
        for (int reg = 0; reg < 4; reg++) {
            int r = wm + i * 16 + quad * 4 + reg;
            if (r < rows_valid) {
                int t = token_index[base + r];
                float* yr = y + (size_t)t * DD + n0 + wn + lcol;
#pragma unroll
                for (int j = 0; j < 4; j++)
                    yr[j * 16] = acc[i][j][reg] + bv[j];
            }
        }
    }
}

// ---------------- host ----------------

extern "C" void kernel_launch(void* const* d_in, const int* in_sizes, int n_in,
                              void* d_out, int out_size, void* d_ws, size_t ws_size,
                              hipStream_t stream) {
    const int*   z = (const int*)d_in[0];
    const float* x = (const float*)d_in[1];
    const float* W = (const float*)d_in[2];
    const float* b = (const float*)d_in[3];
    const int T = in_sizes[0];                 // 65536

    float* zout = (float*)d_out;               // [T] float(z)
    float* y    = (float*)d_out + T;           // [T][512]

    char* ws = (char*)d_ws;
    int*  counts      = (int*)ws;                       // 8 ints @ 0
    int*  cursors     = (int*)(ws + 64);                // 8 ints
    int4* table       = (int4*)(ws + 256);              // <=528 entries
    int*  token_index = (int*)(ws + 16640);             // T ints  (ends 278784)
    unsigned short* Wt = (unsigned short*)(ws + 278784); // 4 MiB   (ends 4473088)
    unsigned short* xg = (unsigned short*)(ws + 4473344);// T*512 bf16 = 64 MiB

    const int max_tiles = T / BM + NEXP;       // 520
    const size_t need = 4473344 + (size_t)T * DD * 2 + 131072; // xg + OOB-read pad

    hipMemsetAsync(ws, 0, 64, stream);
    hist_kernel<<<(T + 255) / 256, 256, 0, stream>>>(z, counts, T);
    convw_kernel<<<dim3(DD / 32, DD / 32, NEXP), 256, 0, stream>>>(W, Wt);
    scan_kernel<<<1, 256, 0, stream>>>(counts, cursors, table, max_tiles);
    scatter_kernel<<<(T + 255) / 256, 256, 0, stream>>>(z, cursors, token_index, zout, T);

    if (ws_size >= need) {
        gather_kernel<<<(T + 3) / 4, 256, 0, stream>>>(x, token_index, xg, T);
        gemm2_kernel<<<dim3(max_tiles, DD / BN), 256, 0, stream>>>(xg, Wt, b, token_index, table, y);
    } else {
        gemm_kernel<<<dim3(max_tiles, DD / BN), 256, 0, stream>>>(x, Wt, b, token_index, table, y);
    }
}